// Round 14
// baseline (207.617 us; speedup 1.0000x reference)
//
#include <hip/hip_runtime.h>
#include <stdint.h>
#include <math.h>

typedef __attribute__((ext_vector_type(8))) short short8;
typedef __attribute__((ext_vector_type(16))) float f32x16;

#define DEVI static __device__ __forceinline__

constexpr int D = 256;  // feature dim
constexpr float LOG2E = 1.4426950408889634f;
constexpr float LN2   = 0.6931471805599453f;

// ws layout (bytes)
constexpr size_t WS_EIMG  = 0;                   // 16 tiles x 16384 = 262144
constexpr size_t WS_ETERM = 262144;              // 512 f32
constexpr size_t WS_WMAX  = 264192;              // 1024 rowblk x 512 col = 2 MB
constexpr size_t WS_WSUM  = WS_WMAX + 2097152;   // 2 MB
constexpr size_t WS_PART  = WS_WSUM + 2097152;   // 128 f32

DEVI unsigned int f2bf(float f) {
  unsigned int u = __float_as_uint(f);
  return (u + 0x7fffu + ((u >> 16) & 1u)) >> 16;  // RNE f32->bf16 (finite)
}
DEVI unsigned int cvtpk(float lo, float hi) {      // 1 instr: 2 f32 -> 2 bf16
  unsigned int r;
  asm("v_cvt_pk_bf16_f32 %0, %1, %2" : "=v"(r) : "v"(lo), "v"(hi));
  return r;
}
DEVI float d4(float4 x) { return x.x*x.x + x.y*x.y + x.z*x.z + x.w*x.w; }
DEVI float shflx(float v, int m) { return __shfl_xor(v, m, 64); }

// ---- prep: e -> B-fragment tile images (32-col tiles, scaled a*log2e) ----
// Tile t covers e-cols [32t, 32t+32). Frag for k-step s, lane (hi,c):
//   byte = t*16384 + s*1024 + (hi*32 + c)*16 holds granule g = 2s+hi
//   (k in [8g, 8g+8)) of col c.   (validated layout, absmax 0)
__global__ void prep_e(const float* __restrict__ e, const float* __restrict__ lsp,
                       char* __restrict__ eimg, float* __restrict__ eterm) {
  const int et = blockIdx.x, t = threadIdx.x;
  const int c = t >> 3, o = t & 7;   // col in tile, octant of 256 k
  const int gc = et * 32 + c;
  const float a = __expf(-2.0f * lsp[0]);
  const float sab = a * LOG2E;       // fold score scale into the image
  const float* s = e + (size_t)gc * D + o * 32;
  float sq = 0.0f;
  unsigned int w[16];
#pragma unroll
  for (int i = 0; i < 8; ++i) {
    float4 x = *(const float4*)(s + i * 4);
    sq += d4(x);
    w[2 * i]     = f2bf(sab * x.x) | (f2bf(sab * x.y) << 16);
    w[2 * i + 1] = f2bf(sab * x.z) | (f2bf(sab * x.w) << 16);
  }
  sq += shflx(sq, 1); sq += shflx(sq, 2); sq += shflx(sq, 4);  // 8-lane group
  char* base = eimg + (size_t)et * 16384;
#pragma unroll
  for (int i = 0; i < 4; ++i) {
    int g = o * 4 + i;  // 16B k-granule
    int phys = (g >> 1) * 1024 + (g & 1) * 512 + c * 16;
    uint4 pk; pk.x = w[4 * i]; pk.y = w[4 * i + 1];
    pk.z = w[4 * i + 2]; pk.w = w[4 * i + 3];
    *(uint4*)(base + phys) = pk;
  }
  if (o == 0) eterm[gc] = -0.5f * a * sq;   // natural-log units
}

// ---- main: 1024 blocks x 512 thr (8 waves). Target: <=64 VGPR -> 8 waves
// per SIMD, 4 blocks/CU ALL resident. Block = 64 z-rows staged once to LDS,
// ONE barrier. Wave task = 64 rows x 32 cols (acc 2xf32x16 = 32 regs,
// 2 MFMA per B-load); 2 sequential tasks cover 64 cols; exact per-task LSE
// written straight to ws. ----
__global__ __launch_bounds__(512, 8)
void lse_main(const float* __restrict__ z, const char* __restrict__ eimg,
              const float* __restrict__ lsp, float* __restrict__ wmax,
              float* __restrict__ wsum) {
  __shared__ char  zbuf[32768];   // 64 rows x 512B, granule-XOR-swizzled
  __shared__ float ztm[64];       // z row terms (log2 units)

  const int tid = threadIdx.x;
  const int wid = tid >> 6, lane = tid & 63;
  const int l31 = lane & 31;      // z-row in row-group; C col = e-col
  const int hi  = lane >> 5;      // k-half of frags; C row-group bit
  const int rowblk = blockIdx.x;
  const float a = __expf(-2.0f * lsp[0]);
  const float ztf = -0.5f * a * LOG2E;

  // ---- stage 64 z-rows: 16 thr/row, thread handles rows srow & srow+32 ----
  {
    const int srow = tid >> 4;          // 0..31
    const int gp = (tid & 15) * 2;      // granule-pair base
    const float* p0 = z + ((size_t)rowblk * 64 + srow) * D + gp * 8;
    const float* p1 = p0 + (size_t)32 * D;
    float4 u0 = *(const float4*)(p0),     u1 = *(const float4*)(p0 + 4);
    float4 u2 = *(const float4*)(p0 + 8), u3 = *(const float4*)(p0 + 12);
    float4 w0 = *(const float4*)(p1),     w1 = *(const float4*)(p1 + 4);
    float4 w2 = *(const float4*)(p1 + 8), w3 = *(const float4*)(p1 + 12);
    float squ = d4(u0) + d4(u1) + d4(u2) + d4(u3);
    float sqw = d4(w0) + d4(w1) + d4(w2) + d4(w3);
    squ += shflx(squ, 1); squ += shflx(squ, 2);
    squ += shflx(squ, 4); squ += shflx(squ, 8);    // 16 thr per row
    sqw += shflx(sqw, 1); sqw += shflx(sqw, 2);
    sqw += shflx(sqw, 4); sqw += shflx(sqw, 8);
    uint4 a0, a1, b0, b1;
    a0.x = cvtpk(u0.x, u0.y); a0.y = cvtpk(u0.z, u0.w);
    a0.z = cvtpk(u1.x, u1.y); a0.w = cvtpk(u1.z, u1.w);
    a1.x = cvtpk(u2.x, u2.y); a1.y = cvtpk(u2.z, u2.w);
    a1.z = cvtpk(u3.x, u3.y); a1.w = cvtpk(u3.z, u3.w);
    b0.x = cvtpk(w0.x, w0.y); b0.y = cvtpk(w0.z, w0.w);
    b0.z = cvtpk(w1.x, w1.y); b0.w = cvtpk(w1.z, w1.w);
    b1.x = cvtpk(w2.x, w2.y); b1.y = cvtpk(w2.z, w2.w);
    b1.z = cvtpk(w3.x, w3.y); b1.w = cvtpk(w3.z, w3.w);
    char* rb = zbuf + srow * 512;       // key = row&31 = srow for both rows
    *(uint4*)(rb + ((gp ^ srow) * 16))               = a0;
    *(uint4*)(rb + (((gp + 1) ^ srow) * 16))         = a1;
    *(uint4*)(rb + 16384 + ((gp ^ srow) * 16))       = b0;
    *(uint4*)(rb + 16384 + (((gp + 1) ^ srow) * 16)) = b1;
    if ((tid & 15) == 0) { ztm[srow] = ztf * squ; ztm[32 + srow] = ztf * sqw; }
  }
  __syncthreads();   // the ONLY barrier

  // addr algebra: l31*512 + ((2s+hi)^l31)*16  ==  C0 ^ (s*32)
  const int C0 = l31 * 512 + ((hi * 16) ^ (l31 * 16));

#pragma unroll 1
  for (int t = 0; t < 2; ++t) {   // task: 32-col tile (t*8 + wid)
    const char* bp = eimg + (size_t)(t * 8 + wid) * 16384 + (size_t)lane * 16;
    short8 Bq0 = *(const short8*)(bp);
    short8 Bq1 = *(const short8*)(bp + 1024);

    f32x16 acc0, acc1;
#pragma unroll
    for (int i = 0; i < 16; ++i) { acc0[i] = 0.f; acc1[i] = 0.f; }
#pragma unroll
    for (int s = 0; s < 16; ++s) {
      short8 Bc = (s & 1) ? Bq1 : Bq0;
      if (s + 2 < 16) {
        short8 nb = *(const short8*)(bp + (s + 2) * 1024);
        if (s & 1) Bq1 = nb; else Bq0 = nb;
      }
      const int slot = C0 ^ (s * 32);
      short8 A0 = *(const short8*)(zbuf + slot);            // rows 0..31
      short8 A1 = *(const short8*)(zbuf + slot + 16384);    // rows 32..63
      acc0 = __builtin_amdgcn_mfma_f32_32x32x16_bf16(A0, Bc, acc0, 0, 0, 0);
      acc1 = __builtin_amdgcn_mfma_f32_32x32x16_bf16(A1, Bc, acc1, 0, 0, 0);
    }

    // epilogue: lane = e-col; exact LSE over the 64 z-rows.
    // C row = rg*32 + (r&3) + 8*(r>>2) + 4*hi -> ztm as float4 at 8j+4hi.
#pragma unroll
    for (int j = 0; j < 4; ++j) {
      float4 z0 = *(const float4*)&ztm[8 * j + 4 * hi];
      float4 z1 = *(const float4*)&ztm[32 + 8 * j + 4 * hi];
      acc0[4 * j]     += z0.x; acc0[4 * j + 1] += z0.y;
      acc0[4 * j + 2] += z0.z; acc0[4 * j + 3] += z0.w;
      acc1[4 * j]     += z1.x; acc1[4 * j + 1] += z1.y;
      acc1[4 * j + 2] += z1.z; acc1[4 * j + 3] += z1.w;
    }
    float m0 = fmaxf(acc0[0], acc1[0]), m1 = fmaxf(acc0[1], acc1[1]);
    float m2 = fmaxf(acc0[2], acc1[2]), m3 = fmaxf(acc0[3], acc1[3]);
#pragma unroll
    for (int i = 4; i < 16; i += 4) {
      m0 = fmaxf(m0, fmaxf(acc0[i], acc1[i]));
      m1 = fmaxf(m1, fmaxf(acc0[i + 1], acc1[i + 1]));
      m2 = fmaxf(m2, fmaxf(acc0[i + 2], acc1[i + 2]));
      m3 = fmaxf(m3, fmaxf(acc0[i + 3], acc1[i + 3]));
    }
    float mx = fmaxf(fmaxf(m0, m1), fmaxf(m2, m3));
    mx = fmaxf(mx, shflx(mx, 32));   // other 32 rows live in partner lane
    float s0 = 0.f, s1 = 0.f, s2 = 0.f, s3 = 0.f;
#pragma unroll
    for (int i = 0; i < 16; i += 4) {
      s0 += exp2f(acc0[i] - mx)     + exp2f(acc1[i] - mx);
      s1 += exp2f(acc0[i + 1] - mx) + exp2f(acc1[i + 1] - mx);
      s2 += exp2f(acc0[i + 2] - mx) + exp2f(acc1[i + 2] - mx);
      s3 += exp2f(acc0[i + 3] - mx) + exp2f(acc1[i + 3] - mx);
    }
    float sm = (s0 + s1) + (s2 + s3);
    sm += shflx(sm, 32);
    if (hi == 0) {   // each col owned by exactly one lane -> direct store
      const int col = t * 256 + wid * 32 + l31;
      wmax[(size_t)rowblk * 512 + col] = mx;   // log2 domain
      wsum[(size_t)rowblk * 512 + col] = sm;
    }
  }
}

// ---- merge the 8 row-blocks of each 512-row window, add eterm, reduce ----
__global__ void merge_b(const float* __restrict__ wmax, const float* __restrict__ wsum,
                        const float* __restrict__ eterm, float* __restrict__ partial) {
  __shared__ float sh[512];
  const int b = blockIdx.x, t = threadIdx.x;
  float m[8];
  float nm = -1e30f;
#pragma unroll
  for (int i = 0; i < 8; ++i) {
    m[i] = wmax[(size_t)(8 * b + i) * 512 + t];
    nm = fmaxf(nm, m[i]);
  }
  float s = 0.0f;
#pragma unroll
  for (int i = 0; i < 8; ++i)
    s += wsum[(size_t)(8 * b + i) * 512 + t] * exp2f(m[i] - nm);
  sh[t] = LN2 * (nm + log2f(s)) + eterm[t];   // back to natural units
  __syncthreads();
  for (int st = 256; st > 0; st >>= 1) {
    if (t < st) sh[t] += sh[t + st];
    __syncthreads();
  }
  if (t == 0) partial[b] = sh[0];
}

__global__ void final_k(const float* __restrict__ partial,
                        const float* __restrict__ lsp, float* __restrict__ out) {
  __shared__ float sh[128];
  const int t = threadIdx.x;
  sh[t] = partial[t];
  __syncthreads();
  for (int st = 64; st > 0; st >>= 1) {
    if (t < st) sh[t] += sh[t + st];
    __syncthreads();
  }
  if (t == 0) {
    float ls = lsp[0];
    out[0] = -sh[0] / 65536.0f + 128.0f * (2.0f * ls - 1.0f) + logf(512.0f);
  }
}

extern "C" void kernel_launch(void* const* d_in, const int* in_sizes, int n_in,
                              void* d_out, int out_size, void* d_ws, size_t ws_size,
                              hipStream_t stream) {
  const float* z   = (const float*)d_in[0];
  const float* e   = (const float*)d_in[1];
  const float* lsp = (const float*)d_in[2];
  float* out = (float*)d_out;
  char* ws = (char*)d_ws;
  char*  eimg    = ws + WS_EIMG;
  float* eterm   = (float*)(ws + WS_ETERM);
  float* wmax    = (float*)(ws + WS_WMAX);
  float* wsum    = (float*)(ws + WS_WSUM);
  float* partial = (float*)(ws + WS_PART);

  prep_e<<<dim3(16), dim3(256), 0, stream>>>(e, lsp, eimg, eterm);
  lse_main<<<dim3(1024), dim3(512), 0, stream>>>(z, eimg, lsp, wmax, wsum);
  merge_b<<<dim3(128), dim3(512), 0, stream>>>(wmax, wsum, eterm, partial);
  final_k<<<dim3(1), dim3(128), 0, stream>>>(partial, lsp, out);
}

// Round 15
// 45.205 us; speedup vs baseline: 4.5928x; 4.5928x over previous
//
#include <hip/hip_runtime.h>
#include <stdint.h>
#include <math.h>

typedef __attribute__((ext_vector_type(8))) short short8;
typedef __attribute__((ext_vector_type(16))) float f32x16;

#define DEVI static __device__ __forceinline__

constexpr int D = 256;  // feature dim
constexpr float LOG2E = 1.4426950408889634f;
constexpr float LN2   = 0.6931471805599453f;

// ws layout (bytes)
constexpr size_t WS_EIMG  = 0;                   // 16 tiles x 16384 = 262144
constexpr size_t WS_ETERM = 262144;              // 512 f32
constexpr size_t WS_WMAX  = 264192;              // 1024 rowblk x 512 col = 2 MB
constexpr size_t WS_WSUM  = WS_WMAX + 2097152;   // 2 MB
constexpr size_t WS_PART  = WS_WSUM + 2097152;   // 128 f32

DEVI unsigned int f2bf(float f) {
  unsigned int u = __float_as_uint(f);
  return (u + 0x7fffu + ((u >> 16) & 1u)) >> 16;  // RNE f32->bf16 (finite)
}
DEVI unsigned int cvtpk(float lo, float hi) {      // 1 instr: 2 f32 -> 2 bf16
  unsigned int r;
  asm("v_cvt_pk_bf16_f32 %0, %1, %2" : "=v"(r) : "v"(lo), "v"(hi));
  return r;
}
DEVI float d4(float4 x) { return x.x*x.x + x.y*x.y + x.z*x.z + x.w*x.w; }
DEVI float shflx(float v, int m) { return __shfl_xor(v, m, 64); }

// ---- prep: e -> B-fragment tile images (32-col tiles, scaled a*log2e) ----
// Tile t covers e-cols [32t, 32t+32). Frag for k-step s, lane (hi,c):
//   byte = t*16384 + s*1024 + (hi*32 + c)*16 holds granule g = 2s+hi
//   (k in [8g, 8g+8)) of col c.   (validated layout, absmax 0)
__global__ void prep_e(const float* __restrict__ e, const float* __restrict__ lsp,
                       char* __restrict__ eimg, float* __restrict__ eterm) {
  const int et = blockIdx.x, t = threadIdx.x;
  const int c = t >> 3, o = t & 7;   // col in tile, octant of 256 k
  const int gc = et * 32 + c;
  const float a = __expf(-2.0f * lsp[0]);
  const float sab = a * LOG2E;       // fold score scale into the image
  const float* s = e + (size_t)gc * D + o * 32;
  float sq = 0.0f;
  unsigned int w[16];
#pragma unroll
  for (int i = 0; i < 8; ++i) {
    float4 x = *(const float4*)(s + i * 4);
    sq += d4(x);
    w[2 * i]     = f2bf(sab * x.x) | (f2bf(sab * x.y) << 16);
    w[2 * i + 1] = f2bf(sab * x.z) | (f2bf(sab * x.w) << 16);
  }
  sq += shflx(sq, 1); sq += shflx(sq, 2); sq += shflx(sq, 4);  // 8-lane group
  char* base = eimg + (size_t)et * 16384;
#pragma unroll
  for (int i = 0; i < 4; ++i) {
    int g = o * 4 + i;  // 16B k-granule
    int phys = (g >> 1) * 1024 + (g & 1) * 512 + c * 16;
    uint4 pk; pk.x = w[4 * i]; pk.y = w[4 * i + 1];
    pk.z = w[4 * i + 2]; pk.w = w[4 * i + 3];
    *(uint4*)(base + phys) = pk;
  }
  if (o == 0) eterm[gc] = -0.5f * a * sq;   // natural-log units
}

// ---- main: 1024 blocks x 512 thr (8 waves; 4 waves/SIMD, 2 blocks/CU).
// Block = 64 z-rows x 512 cols. Stage rows once into LDS -> ONE barrier.
// Wave: task0 (tile wid) MFMA; then task1 (tile 8+wid) MFMA loop with
// task0's epilogue chunks interleaved between unroll groups (in-wave
// MFMA/VALU overlap); then task1 epilogue. Exact per-task LSE -> ws. ----
__global__ __launch_bounds__(512, 4)
void lse_main(const float* __restrict__ z, const char* __restrict__ eimg,
              const float* __restrict__ lsp, float* __restrict__ wmax,
              float* __restrict__ wsum) {
  __shared__ char  zbuf[32768];   // 64 rows x 512B, granule-XOR-swizzled
  __shared__ float ztm[64];       // z row terms (log2 units)

  const int tid = threadIdx.x;
  const int wid = tid >> 6, lane = tid & 63;
  const int l31 = lane & 31;      // z-row in row-group; C col = e-col
  const int hi  = lane >> 5;      // k-half of frags; C row-group bit
  const int rowblk = blockIdx.x;
  const float a = __expf(-2.0f * lsp[0]);
  const float ztf = -0.5f * a * LOG2E;

  // ---- stage 64 z-rows: 16 thr/row, thread handles rows srow & srow+32 ----
  {
    const int srow = tid >> 4;          // 0..31
    const int gp = (tid & 15) * 2;      // granule-pair base
    const float* p0 = z + ((size_t)rowblk * 64 + srow) * D + gp * 8;
    const float* p1 = p0 + (size_t)32 * D;
    float4 u0 = *(const float4*)(p0),     u1 = *(const float4*)(p0 + 4);
    float4 u2 = *(const float4*)(p0 + 8), u3 = *(const float4*)(p0 + 12);
    float4 w0 = *(const float4*)(p1),     w1 = *(const float4*)(p1 + 4);
    float4 w2 = *(const float4*)(p1 + 8), w3 = *(const float4*)(p1 + 12);
    float squ = d4(u0) + d4(u1) + d4(u2) + d4(u3);
    float sqw = d4(w0) + d4(w1) + d4(w2) + d4(w3);
    squ += shflx(squ, 1); squ += shflx(squ, 2);
    squ += shflx(squ, 4); squ += shflx(squ, 8);    // 16 thr per row
    sqw += shflx(sqw, 1); sqw += shflx(sqw, 2);
    sqw += shflx(sqw, 4); sqw += shflx(sqw, 8);
    uint4 a0, a1, b0, b1;
    a0.x = cvtpk(u0.x, u0.y); a0.y = cvtpk(u0.z, u0.w);
    a0.z = cvtpk(u1.x, u1.y); a0.w = cvtpk(u1.z, u1.w);
    a1.x = cvtpk(u2.x, u2.y); a1.y = cvtpk(u2.z, u2.w);
    a1.z = cvtpk(u3.x, u3.y); a1.w = cvtpk(u3.z, u3.w);
    b0.x = cvtpk(w0.x, w0.y); b0.y = cvtpk(w0.z, w0.w);
    b0.z = cvtpk(w1.x, w1.y); b0.w = cvtpk(w1.z, w1.w);
    b1.x = cvtpk(w2.x, w2.y); b1.y = cvtpk(w2.z, w2.w);
    b1.z = cvtpk(w3.x, w3.y); b1.w = cvtpk(w3.z, w3.w);
    char* rb = zbuf + srow * 512;       // key = row&31 = srow for both rows
    *(uint4*)(rb + ((gp ^ srow) * 16))               = a0;
    *(uint4*)(rb + (((gp + 1) ^ srow) * 16))         = a1;
    *(uint4*)(rb + 16384 + ((gp ^ srow) * 16))       = b0;
    *(uint4*)(rb + 16384 + (((gp + 1) ^ srow) * 16)) = b1;
    if ((tid & 15) == 0) { ztm[srow] = ztf * squ; ztm[32 + srow] = ztf * sqw; }
  }
  __syncthreads();   // the ONLY barrier

  // addr algebra: l31*512 + ((2s+hi)^l31)*16  ==  C0 ^ (s*32)
  const int C0 = l31 * 512 + ((hi * 16) ^ (l31 * 16));
  const char* bp0 = eimg + (size_t)wid * 16384 + (size_t)lane * 16;
  const char* bp1 = eimg + (size_t)(8 + wid) * 16384 + (size_t)lane * 16;

  // ================= task 0: MFMA loop (tile wid) =================
  short8 Bq[4];
#pragma unroll
  for (int i = 0; i < 4; ++i) Bq[i] = *(const short8*)(bp0 + i * 1024);
  f32x16 acc0, acc1;
#pragma unroll
  for (int i = 0; i < 16; ++i) { acc0[i] = 0.f; acc1[i] = 0.f; }
#pragma unroll
  for (int s = 0; s < 16; ++s) {
    short8 Bc = Bq[s & 3];
    if (s + 4 < 16) Bq[s & 3] = *(const short8*)(bp0 + (s + 4) * 1024);
    const int slot = C0 ^ (s * 32);
    short8 A0 = *(const short8*)(zbuf + slot);
    short8 A1 = *(const short8*)(zbuf + slot + 16384);
    acc0 = __builtin_amdgcn_mfma_f32_32x32x16_bf16(A0, Bc, acc0, 0, 0, 0);
    acc1 = __builtin_amdgcn_mfma_f32_32x32x16_bf16(A1, Bc, acc1, 0, 0, 0);
  }

  // ===== task 1 MFMA loop (tile 8+wid) with task-0 epilogue interleaved =====
#pragma unroll
  for (int i = 0; i < 4; ++i) Bq[i] = *(const short8*)(bp1 + i * 1024);
  f32x16 acc2, acc3;
#pragma unroll
  for (int i = 0; i < 16; ++i) { acc2[i] = 0.f; acc3[i] = 0.f; }

#define T1STEP(s)                                                            \
  {                                                                          \
    short8 Bc = Bq[(s) & 3];                                                 \
    if ((s) + 4 < 16) Bq[(s) & 3] = *(const short8*)(bp1 + ((s) + 4) * 1024);\
    const int slot = C0 ^ ((s) * 32);                                        \
    short8 A0 = *(const short8*)(zbuf + slot);                               \
    short8 A1 = *(const short8*)(zbuf + slot + 16384);                       \
    acc2 = __builtin_amdgcn_mfma_f32_32x32x16_bf16(A0, Bc, acc2, 0, 0, 0);   \
    acc3 = __builtin_amdgcn_mfma_f32_32x32x16_bf16(A1, Bc, acc3, 0, 0, 0);   \
  }

  float mx0, sm0;
  T1STEP(0) T1STEP(1) T1STEP(2) T1STEP(3)
  // EPI-A: fold zt into acc0/acc1 (C row = rg*32 + (r&3)+8*(r>>2)+4*hi)
#pragma unroll
  for (int j = 0; j < 4; ++j) {
    float4 z0 = *(const float4*)&ztm[8 * j + 4 * hi];
    acc0[4 * j] += z0.x; acc0[4 * j + 1] += z0.y;
    acc0[4 * j + 2] += z0.z; acc0[4 * j + 3] += z0.w;
  }
  T1STEP(4) T1STEP(5)
#pragma unroll
  for (int j = 0; j < 4; ++j) {
    float4 z1 = *(const float4*)&ztm[32 + 8 * j + 4 * hi];
    acc1[4 * j] += z1.x; acc1[4 * j + 1] += z1.y;
    acc1[4 * j + 2] += z1.z; acc1[4 * j + 3] += z1.w;
  }
  T1STEP(6) T1STEP(7)
  {  // EPI-B: max tree (nested fmax -> v_max3 fusion)
    float m0 = fmaxf(fmaxf(acc0[0], acc0[1]), fmaxf(acc0[2], acc0[3]));
    float m1 = fmaxf(fmaxf(acc0[4], acc0[5]), fmaxf(acc0[6], acc0[7]));
    float m2 = fmaxf(fmaxf(acc0[8], acc0[9]), fmaxf(acc0[10], acc0[11]));
    float m3 = fmaxf(fmaxf(acc0[12], acc0[13]), fmaxf(acc0[14], acc0[15]));
    float m4 = fmaxf(fmaxf(acc1[0], acc1[1]), fmaxf(acc1[2], acc1[3]));
    float m5 = fmaxf(fmaxf(acc1[4], acc1[5]), fmaxf(acc1[6], acc1[7]));
    float m6 = fmaxf(fmaxf(acc1[8], acc1[9]), fmaxf(acc1[10], acc1[11]));
    float m7 = fmaxf(fmaxf(acc1[12], acc1[13]), fmaxf(acc1[14], acc1[15]));
    mx0 = fmaxf(fmaxf(fmaxf(m0, m1), fmaxf(m2, m3)),
                fmaxf(fmaxf(m4, m5), fmaxf(m6, m7)));
  }
  T1STEP(8) T1STEP(9)
  mx0 = fmaxf(mx0, shflx(mx0, 32));   // other 32 rows live in partner lane
  T1STEP(10) T1STEP(11)
  {  // EPI-D: exp2 of acc0 half
    float s0 = 0.f, s1 = 0.f, s2 = 0.f, s3 = 0.f;
#pragma unroll
    for (int i = 0; i < 16; i += 4) {
      s0 += exp2f(acc0[i] - mx0);     s1 += exp2f(acc0[i + 1] - mx0);
      s2 += exp2f(acc0[i + 2] - mx0); s3 += exp2f(acc0[i + 3] - mx0);
    }
    sm0 = (s0 + s1) + (s2 + s3);
  }
  T1STEP(12) T1STEP(13) T1STEP(14) T1STEP(15)
#undef T1STEP
  {  // EPI-E: exp2 of acc1 half, merge, store task-0 result
    float s0 = 0.f, s1 = 0.f, s2 = 0.f, s3 = 0.f;
#pragma unroll
    for (int i = 0; i < 16; i += 4) {
      s0 += exp2f(acc1[i] - mx0);     s1 += exp2f(acc1[i + 1] - mx0);
      s2 += exp2f(acc1[i + 2] - mx0); s3 += exp2f(acc1[i + 3] - mx0);
    }
    sm0 += (s0 + s1) + (s2 + s3);
    sm0 += shflx(sm0, 32);
    if (hi == 0) {
      const int col = wid * 32 + l31;
      wmax[(size_t)rowblk * 512 + col] = mx0;   // log2 domain
      wsum[(size_t)rowblk * 512 + col] = sm0;
    }
  }

  // ================= task 1 epilogue (plain) =================
#pragma unroll
  for (int j = 0; j < 4; ++j) {
    float4 z0 = *(const float4*)&ztm[8 * j + 4 * hi];
    float4 z1 = *(const float4*)&ztm[32 + 8 * j + 4 * hi];
    acc2[4 * j]     += z0.x; acc2[4 * j + 1] += z0.y;
    acc2[4 * j + 2] += z0.z; acc2[4 * j + 3] += z0.w;
    acc3[4 * j]     += z1.x; acc3[4 * j + 1] += z1.y;
    acc3[4 * j + 2] += z1.z; acc3[4 * j + 3] += z1.w;
  }
  float mx1;
  {
    float m0 = fmaxf(fmaxf(acc2[0], acc2[1]), fmaxf(acc2[2], acc2[3]));
    float m1 = fmaxf(fmaxf(acc2[4], acc2[5]), fmaxf(acc2[6], acc2[7]));
    float m2 = fmaxf(fmaxf(acc2[8], acc2[9]), fmaxf(acc2[10], acc2[11]));
    float m3 = fmaxf(fmaxf(acc2[12], acc2[13]), fmaxf(acc2[14], acc2[15]));
    float m4 = fmaxf(fmaxf(acc3[0], acc3[1]), fmaxf(acc3[2], acc3[3]));
    float m5 = fmaxf(fmaxf(acc3[4], acc3[5]), fmaxf(acc3[6], acc3[7]));
    float m6 = fmaxf(fmaxf(acc3[8], acc3[9]), fmaxf(acc3[10], acc3[11]));
    float m7 = fmaxf(fmaxf(acc3[12], acc3[13]), fmaxf(acc3[14], acc3[15]));
    mx1 = fmaxf(fmaxf(fmaxf(m0, m1), fmaxf(m2, m3)),
                fmaxf(fmaxf(m4, m5), fmaxf(m6, m7)));
  }
  mx1 = fmaxf(mx1, shflx(mx1, 32));
  {
    float s0 = 0.f, s1 = 0.f, s2 = 0.f, s3 = 0.f;
#pragma unroll
    for (int i = 0; i < 16; i += 4) {
      s0 += exp2f(acc2[i] - mx1)     + exp2f(acc3[i] - mx1);
      s1 += exp2f(acc2[i + 1] - mx1) + exp2f(acc3[i + 1] - mx1);
      s2 += exp2f(acc2[i + 2] - mx1) + exp2f(acc3[i + 2] - mx1);
      s3 += exp2f(acc2[i + 3] - mx1) + exp2f(acc3[i + 3] - mx1);
    }
    float sm1 = (s0 + s1) + (s2 + s3);
    sm1 += shflx(sm1, 32);
    if (hi == 0) {
      const int col = 256 + wid * 32 + l31;
      wmax[(size_t)rowblk * 512 + col] = mx1;
      wsum[(size_t)rowblk * 512 + col] = sm1;
    }
  }
}

// ---- merge the 8 row-blocks of each 512-row window, add eterm, reduce ----
__global__ void merge_b(const float* __restrict__ wmax, const float* __restrict__ wsum,
                        const float* __restrict__ eterm, float* __restrict__ partial) {
  __shared__ float sh[512];
  const int b = blockIdx.x, t = threadIdx.x;
  float m[8];
  float nm = -1e30f;
#pragma unroll
  for (int i = 0; i < 8; ++i) {
    m[i] = wmax[(size_t)(8 * b + i) * 512 + t];
    nm = fmaxf(nm, m[i]);
  }
  float s = 0.0f;
#pragma unroll
  for (int i = 0; i < 8; ++i)
    s += wsum[(size_t)(8 * b + i) * 512 + t] * exp2f(m[i] - nm);
  sh[t] = LN2 * (nm + log2f(s)) + eterm[t];   // back to natural units
  __syncthreads();
  for (int st = 256; st > 0; st >>= 1) {
    if (t < st) sh[t] += sh[t + st];
    __syncthreads();
  }
  if (t == 0) partial[b] = sh[0];
}

__global__ void final_k(const float* __restrict__ partial,
                        const float* __restrict__ lsp, float* __restrict__ out) {
  __shared__ float sh[128];
  const int t = threadIdx.x;
  sh[t] = partial[t];
  __syncthreads();
  for (int st = 64; st > 0; st >>= 1) {
    if (t < st) sh[t] += sh[t + st];
    __syncthreads();
  }
  if (t == 0) {
    float ls = lsp[0];
    out[0] = -sh[0] / 65536.0f + 128.0f * (2.0f * ls - 1.0f) + logf(512.0f);
  }
}

extern "C" void kernel_launch(void* const* d_in, const int* in_sizes, int n_in,
                              void* d_out, int out_size, void* d_ws, size_t ws_size,
                              hipStream_t stream) {
  const float* z   = (const float*)d_in[0];
  const float* e   = (const float*)d_in[1];
  const float* lsp = (const float*)d_in[2];
  float* out = (float*)d_out;
  char* ws = (char*)d_ws;
  char*  eimg    = ws + WS_EIMG;
  float* eterm   = (float*)(ws + WS_ETERM);
  float* wmax    = (float*)(ws + WS_WMAX);
  float* wsum    = (float*)(ws + WS_WSUM);
  float* partial = (float*)(ws + WS_PART);

  prep_e<<<dim3(16), dim3(256), 0, stream>>>(e, lsp, eimg, eterm);
  lse_main<<<dim3(1024), dim3(512), 0, stream>>>(z, eimg, lsp, wmax, wsum);
  merge_b<<<dim3(128), dim3(512), 0, stream>>>(wmax, wsum, eterm, partial);
  final_k<<<dim3(1), dim3(128), 0, stream>>>(partial, lsp, out);
}